// Round 9
// baseline (335.737 us; speedup 1.0000x reference)
//
#include <hip/hip_runtime.h>
#include <hip/hip_fp8.h>
#include <math.h>

#define N_NODES 100000
#define DIM 64
#define NUM_LAYER 3
#define BATCH 4096
#define REG_WEIGHT 1e-4f
#define NBUCKET 391                            // 256-node buckets for scan_convert grid
#define H_SCALE 256.0f                         // fp8 store scale (values pre-scaled by dinv)
#define H_INV_SCALE (1.0f / 256.0f)

typedef float floatx2 __attribute__((ext_vector_type(2)));

// Scratch as device globals. Self-cleaning invariants (for graph replay):
//  - g_deg: all-zero before deg_chains (module-load zero on run 0; place() zeroes
//    it each run after scan_convert has consumed it).
//  - g_shead: 0-sentinel (idx+1). pull mode-2 clears after walking chains.
//  - g_cend: fully rewritten by scan_convert each run (= rp[n]); place() consumes
//    it into rp[n+1] ("end" array); pulls read beg = g_cend[n-1], end = g_cend[n].
// Probe ledger (R3/R6/R8): fixed floor ~84us (2x 256MiB harness poison fills in
// timed region); pulls ~25us each (service-rate bound, ILP-null per R7);
// old stage ~33us + finalize ~16us. R9: global-atomic CSR build (A/B/C),
// no LDS staging round-trip; pulls reverted to R5 4-edge body.
__device__ unsigned char g_hf8[2][(size_t)N_NODES * DIM]; // fp8 ping-pong Hs (scaled)
__device__ float g_sums[(size_t)3 * BATCH * DIM];  // sampled-row accumulators (f32)
__device__ int   g_deg[N_NODES];                   // degree counts (A fills, B reads, C zeroes)
__device__ int   g_cend[N_NODES];                  // B: rp[n]; after C: rp[n+1]
__device__ float g_dinv[N_NODES];                  // deg^-0.5 (400 KB, L2-resident)
__device__ int   g_csr[1280000];                   // final CSR: src only, 4B/edge
__device__ int   g_shead[N_NODES];                 // node -> first sample idx+1 (0 = none)
__device__ int   g_snext[3 * BATCH];               // sample chain links (idx+1, 0 = end)
__device__ float g_part_sp[BATCH];                 // per-wave softplus partials
__device__ float g_part_rg[BATCH];                 // per-wave reg partials

// HW packed fp8 (OCP e4m3 on gfx950) converts: 2 values per instruction.
__device__ inline void fma4_fp8(unsigned int d, float w,
                                float& a0, float& a1, float& a2, float& a3) {
    floatx2 lo = __builtin_amdgcn_cvt_pk_f32_fp8((int)d, false);  // bytes 0,1
    floatx2 hi = __builtin_amdgcn_cvt_pk_f32_fp8((int)d, true);   // bytes 2,3
    a0 = fmaf(w, lo.x, a0); a1 = fmaf(w, lo.y, a1);
    a2 = fmaf(w, hi.x, a2); a3 = fmaf(w, hi.y, a3);
}
__device__ inline unsigned int pack4_fp8(float a0, float a1, float a2, float a3) {
    int w = __builtin_amdgcn_cvt_pk_fp8_f32(a0, a1, 0, false);
    w     = __builtin_amdgcn_cvt_pk_fp8_f32(a2, a3, w, true);
    return (unsigned int)w;
}

// ---- A: degree count via L2 global atomics (low contention: ~13 hits/addr)
//      + sample chain build. No LDS, no staging. ----
__global__ void __launch_bounds__(1024) deg_chains(const int* __restrict__ dst, int E,
                                                   const int* __restrict__ users,
                                                   const int* __restrict__ pos,
                                                   const int* __restrict__ neg) {
    int gt = blockIdx.x * 1024 + threadIdx.x;
    if (gt < 3 * BATCH) {                       // build sample chains (12288 items)
        int which = gt / BATCH, s = gt - which * BATCH;
        const int* idx = (which == 0) ? users : ((which == 1) ? pos : neg);
        g_snext[gt] = atomicExch(&g_shead[idx[s]], gt + 1);   // 0-sentinel links
    }
    int stride = gridDim.x * 1024;
    for (int e = gt; e < E; e += stride)
        atomicAdd(&g_deg[dst[e]], 1);
}

// ---- B: per-bucket (391 blocks x 512). Block b: (1) block-stride sum of
//      deg[0..b*256) -> bucket base (deg array is L2-resident, cheap);
//      (2) LDS scan of own 256 degrees -> g_cend[n] = rp[n], dinv;
//      (3) fused emb->fp8 conversion (Hs0 = SCALE*dinv*emb). Does NOT zero
//      deg (other blocks still reading) -- place() zeroes it. ----
__global__ void __launch_bounds__(512) scan_convert(const float* __restrict__ emb) {
    __shared__ int red[512];
    __shared__ int sc[256];
    __shared__ float ldv[256];
    int b = blockIdx.x, t = threadIdx.x;
    int nbase = b << 8;
    int rows = N_NODES - nbase; if (rows > 256) rows = 256;
    // (1) prefix base: sum of all degrees before this bucket
    int sum = 0;
    for (int i = t; i < nbase; i += 512) sum += g_deg[i];
    red[t] = sum;
    __syncthreads();
    for (int off = 256; off > 0; off >>= 1) {
        if (t < off) red[t] += red[t + off];
        __syncthreads();
    }
    int bbase = red[0];
    // (2) local inclusive scan of this bucket's degrees
    int v = 0;
    if (t < 256) { v = (t < rows) ? g_deg[nbase + t] : 0; sc[t] = v; }
    __syncthreads();
    for (int off = 1; off < 256; off <<= 1) {
        int x = (t >= off && t < 256) ? sc[t - off] : 0;
        __syncthreads();
        if (t < 256) sc[t] += x;
        __syncthreads();
    }
    if (t < rows) {
        g_cend[nbase + t] = bbase + sc[t] - v;                // exclusive start rp[n]
        float dv = (v > 0) ? rsqrtf((float)v) : 0.0f;
        ldv[t] = dv;
        g_dinv[nbase + t] = dv;
    }
    __syncthreads();
    // (3) fused conversion: rows -> Hs0 = SCALE * dinv[row] * emb[row]
    unsigned int* hw = (unsigned int*)g_hf8[0];
    for (int idx = t; idx < rows * 16; idx += 512) {
        int row = idx >> 4, li = idx & 15;
        const float4 ev = *(const float4*)(emb + (size_t)(nbase + row) * DIM + li * 4);
        float s = ldv[row] * H_SCALE;
        hw[(size_t)(nbase + row) * 16 + li] =
            pack4_fp8(ev.x * s, ev.y * s, ev.z * s, ev.w * s);
    }
}

// ---- C: edge placement via per-node global atomic cursors (consumes g_cend:
//      rp[n] -> rp[n+1]) + zero g_deg for next replay. Row order within a node
//      is nondeterministic; exact-safe (fp8-grid values sum exactly in f32). ----
__global__ void __launch_bounds__(1024) place(const int* __restrict__ src,
                                              const int* __restrict__ dst, int E) {
    int gt = blockIdx.x * 1024 + threadIdx.x;
    int stride = gridDim.x * 1024;
    for (int i = gt; i < N_NODES; i += stride) g_deg[i] = 0;  // replay invariant
    for (int e = gt; e < E; e += stride) {
        int p = atomicAdd(&g_cend[dst[e]], 1);
        g_csr[p] = src[e];
    }
}

// ---- pull one layer, FOUR nodes per wave (one 16-lane group per node).
//      Pre-weighted table (Hs = dinv*h): src-only 4B edge stream, no per-edge
//      weight. beg = g_cend[n-1] (rp[n]), end = g_cend[n] (rp[n+1]).
//      mode 1: g_sums = value, keeps chains. mode 2: g_sums += value,
//      consumes chains (g_shead -> 0). ----
__global__ void pull_layer_fp8(const unsigned char* __restrict__ h,
                               unsigned char* __restrict__ hn, int mode) {
    int gid0 = blockIdx.x * blockDim.x + threadIdx.x;
    int wid  = gid0 >> 6;
    int lane = threadIdx.x & 63;
    int g  = lane >> 4;      // group 0..3 -> node
    int li = lane & 15;      // dword index in row
    int n = wid * 4 + g;
    if (n >= N_NODES) return;                    // N_NODES % 4 == 0: whole waves retire
    int end = g_cend[n];
    int beg = (n > 0) ? g_cend[n - 1] : 0;
    float dinvN = g_dinv[n];
    float a0 = 0.f, a1 = 0.f, a2 = 0.f, a3 = 0.f;
    for (int k = beg; k < end; k += 4) {
        int k1 = min(k + 1, end - 1);
        int k2 = min(k + 2, end - 1);
        int k3 = min(k + 3, end - 1);
        int s0 = g_csr[k];
        int s1 = g_csr[k1];
        int s2 = g_csr[k2];
        int s3 = g_csr[k3];
        unsigned int d0 = *(const unsigned int*)(h + (size_t)s0 * DIM + li * 4);
        unsigned int d1 = *(const unsigned int*)(h + (size_t)s1 * DIM + li * 4);
        unsigned int d2 = *(const unsigned int*)(h + (size_t)s2 * DIM + li * 4);
        unsigned int d3 = *(const unsigned int*)(h + (size_t)s3 * DIM + li * 4);
        float w1 = (k + 1 < end) ? 1.0f : 0.0f;
        float w2 = (k + 2 < end) ? 1.0f : 0.0f;
        float w3 = (k + 3 < end) ? 1.0f : 0.0f;
        fma4_fp8(d0, 1.0f, a0, a1, a2, a3);
        fma4_fp8(d1, w1, a0, a1, a2, a3);
        fma4_fp8(d2, w2, a0, a1, a2, a3);
        fma4_fp8(d3, w3, a0, a1, a2, a3);
    }
    float dd = dinvN * dinvN;                    // store next pre-weighted: dinv^2 * a
    *(unsigned int*)(hn + (size_t)n * DIM + li * 4) =
        pack4_fp8(a0 * dd, a1 * dd, a2 * dd, a3 * dd);
    if (mode) {
        float gw = dinvN * H_INV_SCALE;          // unscaled h value = a * dinv / SCALE
        int sidx = g_shead[n];                   // group-uniform chain walk (idx+1)
        while (sidx > 0) {
            int sr = sidx - 1;
            float* sp = &g_sums[(size_t)sr * DIM + li * 4];
            if (mode == 1) {
                sp[0] = a0 * gw; sp[1] = a1 * gw;
                sp[2] = a2 * gw; sp[3] = a3 * gw;
            } else {
                sp[0] += a0 * gw; sp[1] += a1 * gw;
                sp[2] += a2 * gw; sp[3] += a3 * gw;
            }
            sidx = g_snext[sr];
        }
        if (mode == 2 && li == 0) g_shead[n] = 0; // consume chains on layer 2
    }
}

// ---- final layer for sampled rows ONLY (4 samples/wave, same group scheme). ----
__global__ void pull_sampled(const unsigned char* __restrict__ h,
                             const int* __restrict__ users, const int* __restrict__ pos,
                             const int* __restrict__ neg) {
    int gid0 = blockIdx.x * blockDim.x + threadIdx.x;
    int wid  = gid0 >> 6;
    int lane = threadIdx.x & 63;
    int g  = lane >> 4;
    int li = lane & 15;
    int s = wid * 4 + g;
    if (s >= 3 * BATCH) return;
    int which = s >> 12;                         // / BATCH (4096)
    int i     = s & (BATCH - 1);
    const int* idx = (which == 0) ? users : ((which == 1) ? pos : neg);
    int node = idx[i];
    int end = g_cend[node];
    int beg = (node > 0) ? g_cend[node - 1] : 0;
    float dinvN = g_dinv[node];
    float a0 = 0.f, a1 = 0.f, a2 = 0.f, a3 = 0.f;
    for (int k = beg; k < end; k += 4) {
        int k1 = min(k + 1, end - 1);
        int k2 = min(k + 2, end - 1);
        int k3 = min(k + 3, end - 1);
        int s0 = g_csr[k];
        int s1 = g_csr[k1];
        int s2 = g_csr[k2];
        int s3 = g_csr[k3];
        unsigned int d0 = *(const unsigned int*)(h + (size_t)s0 * DIM + li * 4);
        unsigned int d1 = *(const unsigned int*)(h + (size_t)s1 * DIM + li * 4);
        unsigned int d2 = *(const unsigned int*)(h + (size_t)s2 * DIM + li * 4);
        unsigned int d3 = *(const unsigned int*)(h + (size_t)s3 * DIM + li * 4);
        float w1 = (k + 1 < end) ? 1.0f : 0.0f;
        float w2 = (k + 2 < end) ? 1.0f : 0.0f;
        float w3 = (k + 3 < end) ? 1.0f : 0.0f;
        fma4_fp8(d0, 1.0f, a0, a1, a2, a3);
        fma4_fp8(d1, w1, a0, a1, a2, a3);
        fma4_fp8(d2, w2, a0, a1, a2, a3);
        fma4_fp8(d3, w3, a0, a1, a2, a3);
    }
    float gw = dinvN * H_INV_SCALE;
    float* sp = &g_sums[(size_t)s * DIM + li * 4];
    sp[0] += a0 * gw;
    sp[1] += a1 * gw;
    sp[2] += a2 * gw;
    sp[3] += a3 * gw;
}

// ---- per-sample scores + reg; layer-0 (emb) folded in here via u0/p0/n0 ----
__global__ void score_reduce(const float* __restrict__ emb,
                             const int* __restrict__ users, const int* __restrict__ pos,
                             const int* __restrict__ neg) {
    int wid  = (blockIdx.x * blockDim.x + threadIdx.x) >> 6;
    int lane = threadIdx.x & 63;
    if (wid >= BATCH) return;
    float u0 = emb[(size_t)users[wid] * DIM + lane];
    float p0 = emb[(size_t)pos[wid]   * DIM + lane];
    float n0 = emb[(size_t)neg[wid]   * DIM + lane];
    float u = 0.25f * (g_sums[(size_t)wid * DIM + lane] + u0);
    float p = 0.25f * (g_sums[(size_t)(BATCH + wid) * DIM + lane] + p0);
    float n = 0.25f * (g_sums[(size_t)(2 * BATCH + wid) * DIM + lane] + n0);
    float ps = u * p;
    float ns = u * n;
    float rg = u0 * u0 + p0 * p0 + n0 * n0;
    #pragma unroll
    for (int off = 32; off > 0; off >>= 1) {
        ps += __shfl_down(ps, off);
        ns += __shfl_down(ns, off);
        rg += __shfl_down(rg, off);
    }
    if (lane == 0) {
        float x  = ns - ps;
        float sp = fmaxf(x, 0.0f) + log1pf(expf(-fabsf(x)));  // stable softplus
        g_part_sp[wid] = sp;
        g_part_rg[wid] = rg;
    }
}

// ---- single-block final reduction over the 4096 per-wave partials ----
__global__ void final_reduce(float* __restrict__ out) {
    __shared__ float s_sp[256], s_rg[256];
    int t = threadIdx.x;
    float sp = 0.0f, rg = 0.0f;
    for (int i = t; i < BATCH; i += 256) { sp += g_part_sp[i]; rg += g_part_rg[i]; }
    s_sp[t] = sp; s_rg[t] = rg;
    __syncthreads();
    for (int off = 128; off > 0; off >>= 1) {
        if (t < off) { s_sp[t] += s_sp[t + off]; s_rg[t] += s_rg[t + off]; }
        __syncthreads();
    }
    if (t == 0) {
        float loss_emb = s_sp[0] / (float)BATCH;
        float reg      = 0.5f * s_rg[0] / (float)BATCH * REG_WEIGHT;
        out[0] = loss_emb + reg;
        out[1] = loss_emb;
        out[2] = reg;
    }
}

extern "C" void kernel_launch(void* const* d_in, const int* in_sizes, int n_in,
                              void* d_out, int out_size, void* d_ws, size_t ws_size,
                              hipStream_t stream) {
    const float* emb   = (const float*)d_in[0];
    const int*   src   = (const int*)d_in[1];
    const int*   dst   = (const int*)d_in[2];
    const int*   users = (const int*)d_in[3];
    const int*   pos   = (const int*)d_in[4];
    const int*   neg   = (const int*)d_in[5];
    const int E = in_sizes[1];
    float* out = (float*)d_out;

    unsigned char* hf_a;  hipGetSymbolAddress((void**)&hf_a, HIP_SYMBOL(g_hf8));
    unsigned char* hf_b = hf_a + (size_t)N_NODES * DIM;

    const int EDGE_BLOCKS = (E + 4095) / 4096;     // 1024 threads x ~4 edges each
    deg_chains<<<EDGE_BLOCKS, 1024, 0, stream>>>(dst, E, users, pos, neg);
    scan_convert<<<NBUCKET, 512, 0, stream>>>(emb);
    place<<<EDGE_BLOCKS, 1024, 0, stream>>>(src, dst, E);

    const int NQUAD = (N_NODES + 3) / 4;           // 4 nodes per wave
    const int PULL_BLOCKS = (NQUAD * 64 + 255) / 256;

    // layer 1: full pull + sampled gather (assign)
    pull_layer_fp8<<<PULL_BLOCKS, 256, 0, stream>>>(hf_a, hf_b, 1);

    // layer 2: full pull + sampled gather (accumulate) + chain consume
    pull_layer_fp8<<<PULL_BLOCKS, 256, 0, stream>>>(hf_b, hf_a, 2);

    // layer 3 sampled pull (4 samples/wave)
    const int SAMP_BLOCKS = ((3 * BATCH + 3) / 4 * 64 + 255) / 256;
    pull_sampled<<<SAMP_BLOCKS, 256, 0, stream>>>(hf_a, users, pos, neg);

    score_reduce<<<(BATCH * 64 + 255) / 256, 256, 0, stream>>>(emb, users, pos, neg);
    final_reduce<<<1, 256, 0, stream>>>(out);
}

// Round 10
// 247.111 us; speedup vs baseline: 1.3586x; 1.3586x over previous
//
#include <hip/hip_runtime.h>
#include <hip/hip_fp8.h>
#include <math.h>

#define N_NODES 100000
#define DIM 64
#define NUM_LAYER 3
#define BATCH 4096
#define REG_WEIGHT 1e-4f
#define NBUCKET 391                            // dst >> 8 buckets (256 nodes each)
#define STAGE_CAP 4096                         // fixed staging capacity per bucket (14 sigma)
#define CURPAD 16                              // ints: 64B pad per bucket cursor
#define H_SCALE 256.0f                         // fp8 store scale (values pre-scaled by dinv)
#define H_INV_SCALE (1.0f / 256.0f)

typedef float floatx2 __attribute__((ext_vector_type(2)));

// Scratch as device globals. Self-cleaning invariants (for graph replay):
//  - g_bcur: RELATIVE cursors, all-zero before stage_buckets; pull mode-1 re-zeros.
//  - g_shead: 0-sentinel (idx+1); pull mode-2 clears after walking chains.
//  - g_ticket: score-fusion block counter; last block resets to 0.
// Probe ledger: fixed floor ~84us (2x 256MiB harness poison fills in timed
// region); pulls ~25us each (service-rate bound: ILP null R7, CSR variants null
// R7/R9); old stage 33us = stream+hist+RESERVATION STORM (313 blocks x 391
// cursors, atomic-with-return) + scatter; finalize ~16us. R9's global-atomic
// build regressed (place=103us) -> bucket staging restored.
// R10: EPT 8 (157 blocks, halve reservation contention) + fused score/final.
__device__ unsigned char g_hf8[2][(size_t)N_NODES * DIM]; // fp8 ping-pong Hs (scaled)
__device__ float g_sums[(size_t)3 * BATCH * DIM];  // sampled-row accumulators (f32)
__device__ int   g_row_ptr[N_NODES + 1];           // CSR row offsets (by dst)
__device__ float g_dinv[N_NODES];                  // deg^-0.5 (400 KB, L2-resident)
__device__ int   g_bcur[NBUCKET * CURPAD];         // padded bucket staging cursors (relative)
__device__ unsigned int g_stage[NBUCKET * STAGE_CAP]; // packed (src<<8)|(dst&255), 4B/edge
__device__ int   g_csr[1280000];                   // final CSR: src only, 4B/edge
__device__ int   g_shead[N_NODES];                 // node -> first sample idx+1 (0 = none)
__device__ int   g_snext[3 * BATCH];               // sample chain links (idx+1, 0 = end)
__device__ float g_part_sp[BATCH];                 // per-wave softplus partials
__device__ float g_part_rg[BATCH];                 // per-wave reg partials
__device__ int   g_ticket;                         // last-block ticket (self-resetting)

// HW packed fp8 (OCP e4m3 on gfx950) converts: 2 values per instruction.
__device__ inline void fma4_fp8(unsigned int d, float w,
                                float& a0, float& a1, float& a2, float& a3) {
    floatx2 lo = __builtin_amdgcn_cvt_pk_f32_fp8((int)d, false);  // bytes 0,1
    floatx2 hi = __builtin_amdgcn_cvt_pk_f32_fp8((int)d, true);   // bytes 2,3
    a0 = fmaf(w, lo.x, a0); a1 = fmaf(w, lo.y, a1);
    a2 = fmaf(w, hi.x, a2); a3 = fmaf(w, hi.y, a3);
}
__device__ inline unsigned int pack4_fp8(float a0, float a1, float a2, float a3) {
    int w = __builtin_amdgcn_cvt_pk_fp8_f32(a0, a1, 0, false);
    w     = __builtin_amdgcn_cvt_pk_fp8_f32(a2, a3, w, true);
    return (unsigned int)w;
}

// ---- stage pass: LDS histogram -> padded global reservations -> sequential-run
//      4B stores. Also builds the sample chain map (0-sentinel). EPT=8 -> 157
//      blocks: halves the 391-cursor reservation contention vs EPT=4's 313. ----
#define EDGES_PER_THREAD 8
__global__ void __launch_bounds__(1024) stage_buckets(const int* __restrict__ src,
                                                      const int* __restrict__ dst, int E,
                                                      const int* __restrict__ users,
                                                      const int* __restrict__ pos,
                                                      const int* __restrict__ neg) {
    __shared__ int h[NBUCKET];
    __shared__ int cur[NBUCKET];
    int tid = threadIdx.x;
    int gt = blockIdx.x * 1024 + tid;
    if (gt < 3 * BATCH) {                       // build sample chains (12288 items)
        int which = gt / BATCH, s = gt - which * BATCH;
        const int* idx = (which == 0) ? users : ((which == 1) ? pos : neg);
        g_snext[gt] = atomicExch(&g_shead[idx[s]], gt + 1);   // 0-sentinel links
    }
    int base = blockIdx.x * (1024 * EDGES_PER_THREAD);
    for (int i = tid; i < NBUCKET; i += 1024) h[i] = 0;
    __syncthreads();
    int myd[EDGES_PER_THREAD], mys[EDGES_PER_THREAD];
    #pragma unroll
    for (int k = 0; k < EDGES_PER_THREAD; ++k) {
        int e = base + k * 1024 + tid;
        if (e < E) {
            myd[k] = dst[e]; mys[k] = src[e];
            atomicAdd(&h[myd[k] >> 8], 1);
        } else myd[k] = -1;
    }
    __syncthreads();
    for (int i = tid; i < NBUCKET; i += 1024) {
        int c = h[i];
        // relative reservation + absolute bucket base
        cur[i] = c ? (atomicAdd(&g_bcur[i * CURPAD], c) + i * STAGE_CAP) : 0;
    }
    __syncthreads();
    #pragma unroll
    for (int k = 0; k < EDGES_PER_THREAD; ++k) {
        if (myd[k] >= 0) {
            int p = atomicAdd(&cur[myd[k] >> 8], 1);          // LDS cursor -> slot
            g_stage[p] = (unsigned int)((mys[k] << 8) | (myd[k] & 255));
        }
    }
}

// ---- fused per-bucket: 391-scan for base + degree hist + scan -> row_ptr/dinv,
//      scatter into the bucket's CSR window (src only, 4B), THEN convert this
//      bucket's 256 emb rows to the pre-weighted fp8 table Hs0 = dinv*emb. ----
__global__ void __launch_bounds__(512) finalize_place(const float* __restrict__ emb) {
    __shared__ int cs[512];
    __shared__ int lh[256], sc[256], cur[256];
    __shared__ float ldv[256];
    int b = blockIdx.x, t = threadIdx.x;
    int c = (t < NBUCKET) ? g_bcur[t * CURPAD] : 0;           // relative counts
    cs[t] = c;
    __syncthreads();
    for (int off = 1; off < 512; off <<= 1) {
        int x = (t >= off) ? cs[t - off] : 0;
        __syncthreads();
        cs[t] += x;
        __syncthreads();
    }
    int mybase = (b > 0) ? cs[b - 1] : 0;         // exclusive prefix at bucket b
    int cnt    = cs[b] - mybase;
    if (b == 0 && t == 0) g_row_ptr[N_NODES] = cs[NBUCKET - 1];
    int sbeg = b * STAGE_CAP;
    if (t < 256) lh[t] = 0;
    __syncthreads();
    for (int k = t; k < cnt; k += 512)
        atomicAdd(&lh[g_stage[sbeg + k] & 255], 1);
    __syncthreads();
    int v = 0;
    if (t < 256) { v = lh[t]; sc[t] = v; }
    __syncthreads();
    for (int off = 1; off < 256; off <<= 1) {
        int x = (t >= off && t < 256) ? sc[t - off] : 0;
        __syncthreads();
        if (t < 256) sc[t] += x;
        __syncthreads();
    }
    if (t < 256) {
        int start = mybase + sc[t] - v;
        cur[t] = start;
        float dv = (v > 0) ? rsqrtf((float)v) : 0.0f;
        ldv[t] = dv;
        int node = (b << 8) + t;
        if (node < N_NODES) {
            g_row_ptr[node] = start;                          // exclusive
            g_dinv[node]    = dv;
        }
    }
    __syncthreads();
    for (int k = t; k < cnt; k += 512) {                      // staged chunk is L2-hot
        unsigned int e = g_stage[sbeg + k];
        int pos = atomicAdd(&cur[e & 255], 1);
        g_csr[pos] = (int)(e >> 8);                           // src only
    }
    // fused conversion: this bucket's rows -> Hs0 = SCALE * dinv[row] * emb[row]
    {
        int nbase = b << 8;
        int rows = N_NODES - nbase; if (rows > 256) rows = 256;
        unsigned int* hw = (unsigned int*)g_hf8[0];
        for (int idx = t; idx < rows * 16; idx += 512) {
            int row = idx >> 4, li = idx & 15;
            const float4 ev = *(const float4*)(emb + (size_t)(nbase + row) * DIM + li * 4);
            float s = ldv[row] * H_SCALE;
            hw[(size_t)(nbase + row) * 16 + li] =
                pack4_fp8(ev.x * s, ev.y * s, ev.z * s, ev.w * s);
        }
    }
}

// ---- pull one layer, FOUR nodes per wave (one 16-lane group per node).
//      Pre-weighted table (Hs = dinv*h): src-only 4B edge stream, no per-edge
//      weight. mode 1: g_sums = value, resets g_bcur, keeps chains.
//      mode 2: g_sums += value, consumes chains (g_shead -> 0). ----
__global__ void pull_layer_fp8(const unsigned char* __restrict__ h,
                               unsigned char* __restrict__ hn, int mode) {
    int gid0 = blockIdx.x * blockDim.x + threadIdx.x;
    if (mode == 1 && gid0 < NBUCKET) g_bcur[gid0 * CURPAD] = 0;  // reset for next replay
    int wid  = gid0 >> 6;
    int lane = threadIdx.x & 63;
    int g  = lane >> 4;      // group 0..3 -> node
    int li = lane & 15;      // dword index in row
    int n = wid * 4 + g;
    if (n >= N_NODES) return;                    // N_NODES % 4 == 0: whole waves retire
    int beg = g_row_ptr[n], end = g_row_ptr[n + 1];
    float dinvN = g_dinv[n];
    float a0 = 0.f, a1 = 0.f, a2 = 0.f, a3 = 0.f;
    for (int k = beg; k < end; k += 4) {
        int k1 = min(k + 1, end - 1);
        int k2 = min(k + 2, end - 1);
        int k3 = min(k + 3, end - 1);
        int s0 = g_csr[k];
        int s1 = g_csr[k1];
        int s2 = g_csr[k2];
        int s3 = g_csr[k3];
        unsigned int d0 = *(const unsigned int*)(h + (size_t)s0 * DIM + li * 4);
        unsigned int d1 = *(const unsigned int*)(h + (size_t)s1 * DIM + li * 4);
        unsigned int d2 = *(const unsigned int*)(h + (size_t)s2 * DIM + li * 4);
        unsigned int d3 = *(const unsigned int*)(h + (size_t)s3 * DIM + li * 4);
        float w1 = (k + 1 < end) ? 1.0f : 0.0f;
        float w2 = (k + 2 < end) ? 1.0f : 0.0f;
        float w3 = (k + 3 < end) ? 1.0f : 0.0f;
        fma4_fp8(d0, 1.0f, a0, a1, a2, a3);
        fma4_fp8(d1, w1, a0, a1, a2, a3);
        fma4_fp8(d2, w2, a0, a1, a2, a3);
        fma4_fp8(d3, w3, a0, a1, a2, a3);
    }
    float dd = dinvN * dinvN;                    // store next pre-weighted: dinv^2 * a
    *(unsigned int*)(hn + (size_t)n * DIM + li * 4) =
        pack4_fp8(a0 * dd, a1 * dd, a2 * dd, a3 * dd);
    if (mode) {
        float gw = dinvN * H_INV_SCALE;          // unscaled h value = a * dinv / SCALE
        int sidx = g_shead[n];                   // group-uniform chain walk (idx+1)
        while (sidx > 0) {
            int sr = sidx - 1;
            float* sp = &g_sums[(size_t)sr * DIM + li * 4];
            if (mode == 1) {
                sp[0] = a0 * gw; sp[1] = a1 * gw;
                sp[2] = a2 * gw; sp[3] = a3 * gw;
            } else {
                sp[0] += a0 * gw; sp[1] += a1 * gw;
                sp[2] += a2 * gw; sp[3] += a3 * gw;
            }
            sidx = g_snext[sr];
        }
        if (mode == 2 && li == 0) g_shead[n] = 0; // consume chains on layer 2
    }
}

// ---- final layer for sampled rows ONLY (4 samples/wave, same group scheme). ----
__global__ void pull_sampled(const unsigned char* __restrict__ h,
                             const int* __restrict__ users, const int* __restrict__ pos,
                             const int* __restrict__ neg) {
    int gid0 = blockIdx.x * blockDim.x + threadIdx.x;
    int wid  = gid0 >> 6;
    int lane = threadIdx.x & 63;
    int g  = lane >> 4;
    int li = lane & 15;
    int s = wid * 4 + g;
    if (s >= 3 * BATCH) return;
    int which = s >> 12;                         // / BATCH (4096)
    int i     = s & (BATCH - 1);
    const int* idx = (which == 0) ? users : ((which == 1) ? pos : neg);
    int node = idx[i];
    int beg = g_row_ptr[node], end = g_row_ptr[node + 1];
    float dinvN = g_dinv[node];
    float a0 = 0.f, a1 = 0.f, a2 = 0.f, a3 = 0.f;
    for (int k = beg; k < end; k += 4) {
        int k1 = min(k + 1, end - 1);
        int k2 = min(k + 2, end - 1);
        int k3 = min(k + 3, end - 1);
        int s0 = g_csr[k];
        int s1 = g_csr[k1];
        int s2 = g_csr[k2];
        int s3 = g_csr[k3];
        unsigned int d0 = *(const unsigned int*)(h + (size_t)s0 * DIM + li * 4);
        unsigned int d1 = *(const unsigned int*)(h + (size_t)s1 * DIM + li * 4);
        unsigned int d2 = *(const unsigned int*)(h + (size_t)s2 * DIM + li * 4);
        unsigned int d3 = *(const unsigned int*)(h + (size_t)s3 * DIM + li * 4);
        float w1 = (k + 1 < end) ? 1.0f : 0.0f;
        float w2 = (k + 2 < end) ? 1.0f : 0.0f;
        float w3 = (k + 3 < end) ? 1.0f : 0.0f;
        fma4_fp8(d0, 1.0f, a0, a1, a2, a3);
        fma4_fp8(d1, w1, a0, a1, a2, a3);
        fma4_fp8(d2, w2, a0, a1, a2, a3);
        fma4_fp8(d3, w3, a0, a1, a2, a3);
    }
    float gw = dinvN * H_INV_SCALE;
    float* sp = &g_sums[(size_t)s * DIM + li * 4];
    sp[0] += a0 * gw;
    sp[1] += a1 * gw;
    sp[2] += a2 * gw;
    sp[3] += a3 * gw;
}

// ---- per-sample scores + reg (layer-0 folded via u0/p0/n0), FUSED final
//      reduction: per-wave partials -> ticket -> last block reduces 4096
//      partials and writes out. Ticket self-resets for graph replay. ----
__global__ void __launch_bounds__(256) score_reduce(const float* __restrict__ emb,
                                                    const int* __restrict__ users,
                                                    const int* __restrict__ pos,
                                                    const int* __restrict__ neg,
                                                    float* __restrict__ out) {
    int wid  = (blockIdx.x * blockDim.x + threadIdx.x) >> 6;
    int lane = threadIdx.x & 63;
    __shared__ int s_last;
    if (wid < BATCH) {
        float u0 = emb[(size_t)users[wid] * DIM + lane];
        float p0 = emb[(size_t)pos[wid]   * DIM + lane];
        float n0 = emb[(size_t)neg[wid]   * DIM + lane];
        float u = 0.25f * (g_sums[(size_t)wid * DIM + lane] + u0);
        float p = 0.25f * (g_sums[(size_t)(BATCH + wid) * DIM + lane] + p0);
        float n = 0.25f * (g_sums[(size_t)(2 * BATCH + wid) * DIM + lane] + n0);
        float ps = u * p;
        float ns = u * n;
        float rg = u0 * u0 + p0 * p0 + n0 * n0;
        #pragma unroll
        for (int off = 32; off > 0; off >>= 1) {
            ps += __shfl_down(ps, off);
            ns += __shfl_down(ns, off);
            rg += __shfl_down(rg, off);
        }
        if (lane == 0) {
            float x  = ns - ps;
            float sp = fmaxf(x, 0.0f) + log1pf(expf(-fabsf(x)));  // stable softplus
            g_part_sp[wid] = sp;
            g_part_rg[wid] = rg;
        }
    }
    // last-block final reduction (release: fence before ticket; acquire: fence after)
    __threadfence();
    __syncthreads();
    if (threadIdx.x == 0) s_last = atomicAdd(&g_ticket, 1);
    __syncthreads();
    int nblk = (BATCH * 64) / 256;               // 1024 blocks
    if (s_last == nblk - 1) {
        __threadfence();
        __shared__ float s_sp[256], s_rg[256];
        int t = threadIdx.x;
        float sp = 0.0f, rg = 0.0f;
        for (int i = t; i < BATCH; i += 256) { sp += g_part_sp[i]; rg += g_part_rg[i]; }
        s_sp[t] = sp; s_rg[t] = rg;
        __syncthreads();
        for (int off = 128; off > 0; off >>= 1) {
            if (t < off) { s_sp[t] += s_sp[t + off]; s_rg[t] += s_rg[t + off]; }
            __syncthreads();
        }
        if (t == 0) {
            float loss_emb = s_sp[0] / (float)BATCH;
            float reg      = 0.5f * s_rg[0] / (float)BATCH * REG_WEIGHT;
            out[0] = loss_emb + reg;
            out[1] = loss_emb;
            out[2] = reg;
            g_ticket = 0;                        // restore replay invariant
        }
    }
}

extern "C" void kernel_launch(void* const* d_in, const int* in_sizes, int n_in,
                              void* d_out, int out_size, void* d_ws, size_t ws_size,
                              hipStream_t stream) {
    const float* emb   = (const float*)d_in[0];
    const int*   src   = (const int*)d_in[1];
    const int*   dst   = (const int*)d_in[2];
    const int*   users = (const int*)d_in[3];
    const int*   pos   = (const int*)d_in[4];
    const int*   neg   = (const int*)d_in[5];
    const int E = in_sizes[1];
    float* out = (float*)d_out;

    unsigned char* hf_a;  hipGetSymbolAddress((void**)&hf_a, HIP_SYMBOL(g_hf8));
    unsigned char* hf_b = hf_a + (size_t)N_NODES * DIM;

    const int STAGE_BLOCKS = (E + 1024 * EDGES_PER_THREAD - 1) / (1024 * EDGES_PER_THREAD);
    stage_buckets<<<STAGE_BLOCKS, 1024, 0, stream>>>(src, dst, E, users, pos, neg);
    finalize_place<<<NBUCKET, 512, 0, stream>>>(emb);

    const int NQUAD = (N_NODES + 3) / 4;           // 4 nodes per wave
    const int PULL_BLOCKS = (NQUAD * 64 + 255) / 256;

    // layer 1: full pull + sampled gather (assign) + bcur reset
    pull_layer_fp8<<<PULL_BLOCKS, 256, 0, stream>>>(hf_a, hf_b, 1);

    // layer 2: full pull + sampled gather (accumulate) + chain consume
    pull_layer_fp8<<<PULL_BLOCKS, 256, 0, stream>>>(hf_b, hf_a, 2);

    // layer 3 sampled pull (4 samples/wave)
    const int SAMP_BLOCKS = ((3 * BATCH + 3) / 4 * 64 + 255) / 256;
    pull_sampled<<<SAMP_BLOCKS, 256, 0, stream>>>(hf_a, users, pos, neg);

    // fused scores + final reduction (last-block ticket)
    score_reduce<<<(BATCH * 64) / 256, 256, 0, stream>>>(emb, users, pos, neg, out);
}

// Round 11
// 181.571 us; speedup vs baseline: 1.8491x; 1.3610x over previous
//
#include <hip/hip_runtime.h>
#include <hip/hip_fp8.h>
#include <math.h>

#define N_NODES 100000
#define DIM 64
#define NUM_LAYER 3
#define BATCH 4096
#define REG_WEIGHT 1e-4f
#define NBUCKET 391                            // dst >> 8 buckets (256 nodes each)
#define STAGE_CAP 4096                         // fixed staging capacity per bucket (14 sigma)
#define CURPAD 16                              // ints: 64B pad per bucket cursor
#define H_SCALE 256.0f                         // fp8 store scale (values pre-scaled by dinv)
#define H_INV_SCALE (1.0f / 256.0f)

typedef float floatx2 __attribute__((ext_vector_type(2)));

// Scratch as device globals. Self-cleaning invariants (for graph replay):
//  - g_bcur: RELATIVE cursors, all-zero before stage_buckets; pull mode-1 re-zeros.
//  - g_shead: 0-sentinel (idx+1); pull mode-2 clears after walking chains.
// Probe ledger: fixed floor ~84us (2x 256MiB harness poison fills in timed
// region); pulls ~25us each (service-rate bound: ILP null R7, CSR variants
// null/regressed R7/R9); finalize ~16us; stage 33us@EPT4 -> ~21us@EPT8
// (reservation-cursor contention halved, R10 back-solve). R10's ticket-fused
// final reduction REGRESSED +74us: device-scope __threadfence in 1024 blocks
// = cross-XCD L2 writeback storm on 8-XCD gfx950. Kernel boundary is the
// cheap fence -> score/final stay separate kernels.
__device__ unsigned char g_hf8[2][(size_t)N_NODES * DIM]; // fp8 ping-pong Hs (scaled)
__device__ float g_sums[(size_t)3 * BATCH * DIM];  // sampled-row accumulators (f32)
__device__ int   g_row_ptr[N_NODES + 1];           // CSR row offsets (by dst)
__device__ float g_dinv[N_NODES];                  // deg^-0.5 (400 KB, L2-resident)
__device__ int   g_bcur[NBUCKET * CURPAD];         // padded bucket staging cursors (relative)
__device__ unsigned int g_stage[NBUCKET * STAGE_CAP]; // packed (src<<8)|(dst&255), 4B/edge
__device__ int   g_csr[1280000];                   // final CSR: src only, 4B/edge
__device__ int   g_shead[N_NODES];                 // node -> first sample idx+1 (0 = none)
__device__ int   g_snext[3 * BATCH];               // sample chain links (idx+1, 0 = end)
__device__ float g_part_sp[BATCH];                 // per-wave softplus partials
__device__ float g_part_rg[BATCH];                 // per-wave reg partials

// HW packed fp8 (OCP e4m3 on gfx950) converts: 2 values per instruction.
__device__ inline void fma4_fp8(unsigned int d, float w,
                                float& a0, float& a1, float& a2, float& a3) {
    floatx2 lo = __builtin_amdgcn_cvt_pk_f32_fp8((int)d, false);  // bytes 0,1
    floatx2 hi = __builtin_amdgcn_cvt_pk_f32_fp8((int)d, true);   // bytes 2,3
    a0 = fmaf(w, lo.x, a0); a1 = fmaf(w, lo.y, a1);
    a2 = fmaf(w, hi.x, a2); a3 = fmaf(w, hi.y, a3);
}
__device__ inline unsigned int pack4_fp8(float a0, float a1, float a2, float a3) {
    int w = __builtin_amdgcn_cvt_pk_fp8_f32(a0, a1, 0, false);
    w     = __builtin_amdgcn_cvt_pk_fp8_f32(a2, a3, w, true);
    return (unsigned int)w;
}

// ---- stage pass: LDS histogram -> padded global reservations -> sequential-run
//      4B stores. Also builds the sample chain map (0-sentinel). EPT=8 -> 157
//      blocks: halves the 391-cursor reservation contention vs EPT=4's 313
//      (R10 back-solve: ~-12us). ----
#define EDGES_PER_THREAD 8
__global__ void __launch_bounds__(1024) stage_buckets(const int* __restrict__ src,
                                                      const int* __restrict__ dst, int E,
                                                      const int* __restrict__ users,
                                                      const int* __restrict__ pos,
                                                      const int* __restrict__ neg) {
    __shared__ int h[NBUCKET];
    __shared__ int cur[NBUCKET];
    int tid = threadIdx.x;
    int gt = blockIdx.x * 1024 + tid;
    if (gt < 3 * BATCH) {                       // build sample chains (12288 items)
        int which = gt / BATCH, s = gt - which * BATCH;
        const int* idx = (which == 0) ? users : ((which == 1) ? pos : neg);
        g_snext[gt] = atomicExch(&g_shead[idx[s]], gt + 1);   // 0-sentinel links
    }
    int base = blockIdx.x * (1024 * EDGES_PER_THREAD);
    for (int i = tid; i < NBUCKET; i += 1024) h[i] = 0;
    __syncthreads();
    int myd[EDGES_PER_THREAD], mys[EDGES_PER_THREAD];
    #pragma unroll
    for (int k = 0; k < EDGES_PER_THREAD; ++k) {
        int e = base + k * 1024 + tid;
        if (e < E) {
            myd[k] = dst[e]; mys[k] = src[e];
            atomicAdd(&h[myd[k] >> 8], 1);
        } else myd[k] = -1;
    }
    __syncthreads();
    for (int i = tid; i < NBUCKET; i += 1024) {
        int c = h[i];
        // relative reservation + absolute bucket base
        cur[i] = c ? (atomicAdd(&g_bcur[i * CURPAD], c) + i * STAGE_CAP) : 0;
    }
    __syncthreads();
    #pragma unroll
    for (int k = 0; k < EDGES_PER_THREAD; ++k) {
        if (myd[k] >= 0) {
            int p = atomicAdd(&cur[myd[k] >> 8], 1);          // LDS cursor -> slot
            g_stage[p] = (unsigned int)((mys[k] << 8) | (myd[k] & 255));
        }
    }
}

// ---- fused per-bucket: 391-scan for base + degree hist + scan -> row_ptr/dinv,
//      scatter into the bucket's CSR window (src only, 4B), THEN convert this
//      bucket's 256 emb rows to the pre-weighted fp8 table Hs0 = dinv*emb. ----
__global__ void __launch_bounds__(512) finalize_place(const float* __restrict__ emb) {
    __shared__ int cs[512];
    __shared__ int lh[256], sc[256], cur[256];
    __shared__ float ldv[256];
    int b = blockIdx.x, t = threadIdx.x;
    int c = (t < NBUCKET) ? g_bcur[t * CURPAD] : 0;           // relative counts
    cs[t] = c;
    __syncthreads();
    for (int off = 1; off < 512; off <<= 1) {
        int x = (t >= off) ? cs[t - off] : 0;
        __syncthreads();
        cs[t] += x;
        __syncthreads();
    }
    int mybase = (b > 0) ? cs[b - 1] : 0;         // exclusive prefix at bucket b
    int cnt    = cs[b] - mybase;
    if (b == 0 && t == 0) g_row_ptr[N_NODES] = cs[NBUCKET - 1];
    int sbeg = b * STAGE_CAP;
    if (t < 256) lh[t] = 0;
    __syncthreads();
    for (int k = t; k < cnt; k += 512)
        atomicAdd(&lh[g_stage[sbeg + k] & 255], 1);
    __syncthreads();
    int v = 0;
    if (t < 256) { v = lh[t]; sc[t] = v; }
    __syncthreads();
    for (int off = 1; off < 256; off <<= 1) {
        int x = (t >= off && t < 256) ? sc[t - off] : 0;
        __syncthreads();
        if (t < 256) sc[t] += x;
        __syncthreads();
    }
    if (t < 256) {
        int start = mybase + sc[t] - v;
        cur[t] = start;
        float dv = (v > 0) ? rsqrtf((float)v) : 0.0f;
        ldv[t] = dv;
        int node = (b << 8) + t;
        if (node < N_NODES) {
            g_row_ptr[node] = start;                          // exclusive
            g_dinv[node]    = dv;
        }
    }
    __syncthreads();
    for (int k = t; k < cnt; k += 512) {                      // staged chunk is L2-hot
        unsigned int e = g_stage[sbeg + k];
        int pos = atomicAdd(&cur[e & 255], 1);
        g_csr[pos] = (int)(e >> 8);                           // src only
    }
    // fused conversion: this bucket's rows -> Hs0 = SCALE * dinv[row] * emb[row]
    {
        int nbase = b << 8;
        int rows = N_NODES - nbase; if (rows > 256) rows = 256;
        unsigned int* hw = (unsigned int*)g_hf8[0];
        for (int idx = t; idx < rows * 16; idx += 512) {
            int row = idx >> 4, li = idx & 15;
            const float4 ev = *(const float4*)(emb + (size_t)(nbase + row) * DIM + li * 4);
            float s = ldv[row] * H_SCALE;
            hw[(size_t)(nbase + row) * 16 + li] =
                pack4_fp8(ev.x * s, ev.y * s, ev.z * s, ev.w * s);
        }
    }
}

// ---- pull one layer, FOUR nodes per wave (one 16-lane group per node).
//      Pre-weighted table (Hs = dinv*h): src-only 4B edge stream, no per-edge
//      weight. mode 1: g_sums = value, resets g_bcur, keeps chains.
//      mode 2: g_sums += value, consumes chains (g_shead -> 0). ----
__global__ void pull_layer_fp8(const unsigned char* __restrict__ h,
                               unsigned char* __restrict__ hn, int mode) {
    int gid0 = blockIdx.x * blockDim.x + threadIdx.x;
    if (mode == 1 && gid0 < NBUCKET) g_bcur[gid0 * CURPAD] = 0;  // reset for next replay
    int wid  = gid0 >> 6;
    int lane = threadIdx.x & 63;
    int g  = lane >> 4;      // group 0..3 -> node
    int li = lane & 15;      // dword index in row
    int n = wid * 4 + g;
    if (n >= N_NODES) return;                    // N_NODES % 4 == 0: whole waves retire
    int beg = g_row_ptr[n], end = g_row_ptr[n + 1];
    float dinvN = g_dinv[n];
    float a0 = 0.f, a1 = 0.f, a2 = 0.f, a3 = 0.f;
    for (int k = beg; k < end; k += 4) {
        int k1 = min(k + 1, end - 1);
        int k2 = min(k + 2, end - 1);
        int k3 = min(k + 3, end - 1);
        int s0 = g_csr[k];
        int s1 = g_csr[k1];
        int s2 = g_csr[k2];
        int s3 = g_csr[k3];
        unsigned int d0 = *(const unsigned int*)(h + (size_t)s0 * DIM + li * 4);
        unsigned int d1 = *(const unsigned int*)(h + (size_t)s1 * DIM + li * 4);
        unsigned int d2 = *(const unsigned int*)(h + (size_t)s2 * DIM + li * 4);
        unsigned int d3 = *(const unsigned int*)(h + (size_t)s3 * DIM + li * 4);
        float w1 = (k + 1 < end) ? 1.0f : 0.0f;
        float w2 = (k + 2 < end) ? 1.0f : 0.0f;
        float w3 = (k + 3 < end) ? 1.0f : 0.0f;
        fma4_fp8(d0, 1.0f, a0, a1, a2, a3);
        fma4_fp8(d1, w1, a0, a1, a2, a3);
        fma4_fp8(d2, w2, a0, a1, a2, a3);
        fma4_fp8(d3, w3, a0, a1, a2, a3);
    }
    float dd = dinvN * dinvN;                    // store next pre-weighted: dinv^2 * a
    *(unsigned int*)(hn + (size_t)n * DIM + li * 4) =
        pack4_fp8(a0 * dd, a1 * dd, a2 * dd, a3 * dd);
    if (mode) {
        float gw = dinvN * H_INV_SCALE;          // unscaled h value = a * dinv / SCALE
        int sidx = g_shead[n];                   // group-uniform chain walk (idx+1)
        while (sidx > 0) {
            int sr = sidx - 1;
            float* sp = &g_sums[(size_t)sr * DIM + li * 4];
            if (mode == 1) {
                sp[0] = a0 * gw; sp[1] = a1 * gw;
                sp[2] = a2 * gw; sp[3] = a3 * gw;
            } else {
                sp[0] += a0 * gw; sp[1] += a1 * gw;
                sp[2] += a2 * gw; sp[3] += a3 * gw;
            }
            sidx = g_snext[sr];
        }
        if (mode == 2 && li == 0) g_shead[n] = 0; // consume chains on layer 2
    }
}

// ---- final layer for sampled rows ONLY (4 samples/wave, same group scheme). ----
__global__ void pull_sampled(const unsigned char* __restrict__ h,
                             const int* __restrict__ users, const int* __restrict__ pos,
                             const int* __restrict__ neg) {
    int gid0 = blockIdx.x * blockDim.x + threadIdx.x;
    int wid  = gid0 >> 6;
    int lane = threadIdx.x & 63;
    int g  = lane >> 4;
    int li = lane & 15;
    int s = wid * 4 + g;
    if (s >= 3 * BATCH) return;
    int which = s >> 12;                         // / BATCH (4096)
    int i     = s & (BATCH - 1);
    const int* idx = (which == 0) ? users : ((which == 1) ? pos : neg);
    int node = idx[i];
    int beg = g_row_ptr[node], end = g_row_ptr[node + 1];
    float dinvN = g_dinv[node];
    float a0 = 0.f, a1 = 0.f, a2 = 0.f, a3 = 0.f;
    for (int k = beg; k < end; k += 4) {
        int k1 = min(k + 1, end - 1);
        int k2 = min(k + 2, end - 1);
        int k3 = min(k + 3, end - 1);
        int s0 = g_csr[k];
        int s1 = g_csr[k1];
        int s2 = g_csr[k2];
        int s3 = g_csr[k3];
        unsigned int d0 = *(const unsigned int*)(h + (size_t)s0 * DIM + li * 4);
        unsigned int d1 = *(const unsigned int*)(h + (size_t)s1 * DIM + li * 4);
        unsigned int d2 = *(const unsigned int*)(h + (size_t)s2 * DIM + li * 4);
        unsigned int d3 = *(const unsigned int*)(h + (size_t)s3 * DIM + li * 4);
        float w1 = (k + 1 < end) ? 1.0f : 0.0f;
        float w2 = (k + 2 < end) ? 1.0f : 0.0f;
        float w3 = (k + 3 < end) ? 1.0f : 0.0f;
        fma4_fp8(d0, 1.0f, a0, a1, a2, a3);
        fma4_fp8(d1, w1, a0, a1, a2, a3);
        fma4_fp8(d2, w2, a0, a1, a2, a3);
        fma4_fp8(d3, w3, a0, a1, a2, a3);
    }
    float gw = dinvN * H_INV_SCALE;
    float* sp = &g_sums[(size_t)s * DIM + li * 4];
    sp[0] += a0 * gw;
    sp[1] += a1 * gw;
    sp[2] += a2 * gw;
    sp[3] += a3 * gw;
}

// ---- per-sample scores + reg; layer-0 (emb) folded in here via u0/p0/n0 ----
__global__ void score_reduce(const float* __restrict__ emb,
                             const int* __restrict__ users, const int* __restrict__ pos,
                             const int* __restrict__ neg) {
    int wid  = (blockIdx.x * blockDim.x + threadIdx.x) >> 6;
    int lane = threadIdx.x & 63;
    if (wid >= BATCH) return;
    float u0 = emb[(size_t)users[wid] * DIM + lane];
    float p0 = emb[(size_t)pos[wid]   * DIM + lane];
    float n0 = emb[(size_t)neg[wid]   * DIM + lane];
    float u = 0.25f * (g_sums[(size_t)wid * DIM + lane] + u0);
    float p = 0.25f * (g_sums[(size_t)(BATCH + wid) * DIM + lane] + p0);
    float n = 0.25f * (g_sums[(size_t)(2 * BATCH + wid) * DIM + lane] + n0);
    float ps = u * p;
    float ns = u * n;
    float rg = u0 * u0 + p0 * p0 + n0 * n0;
    #pragma unroll
    for (int off = 32; off > 0; off >>= 1) {
        ps += __shfl_down(ps, off);
        ns += __shfl_down(ns, off);
        rg += __shfl_down(rg, off);
    }
    if (lane == 0) {
        float x  = ns - ps;
        float sp = fmaxf(x, 0.0f) + log1pf(expf(-fabsf(x)));  // stable softplus
        g_part_sp[wid] = sp;
        g_part_rg[wid] = rg;
    }
}

// ---- single-block final reduction over the 4096 per-wave partials ----
__global__ void final_reduce(float* __restrict__ out) {
    __shared__ float s_sp[256], s_rg[256];
    int t = threadIdx.x;
    float sp = 0.0f, rg = 0.0f;
    for (int i = t; i < BATCH; i += 256) { sp += g_part_sp[i]; rg += g_part_rg[i]; }
    s_sp[t] = sp; s_rg[t] = rg;
    __syncthreads();
    for (int off = 128; off > 0; off >>= 1) {
        if (t < off) { s_sp[t] += s_sp[t + off]; s_rg[t] += s_rg[t + off]; }
        __syncthreads();
    }
    if (t == 0) {
        float loss_emb = s_sp[0] / (float)BATCH;
        float reg      = 0.5f * s_rg[0] / (float)BATCH * REG_WEIGHT;
        out[0] = loss_emb + reg;
        out[1] = loss_emb;
        out[2] = reg;
    }
}

extern "C" void kernel_launch(void* const* d_in, const int* in_sizes, int n_in,
                              void* d_out, int out_size, void* d_ws, size_t ws_size,
                              hipStream_t stream) {
    const float* emb   = (const float*)d_in[0];
    const int*   src   = (const int*)d_in[1];
    const int*   dst   = (const int*)d_in[2];
    const int*   users = (const int*)d_in[3];
    const int*   pos   = (const int*)d_in[4];
    const int*   neg   = (const int*)d_in[5];
    const int E = in_sizes[1];
    float* out = (float*)d_out;

    unsigned char* hf_a;  hipGetSymbolAddress((void**)&hf_a, HIP_SYMBOL(g_hf8));
    unsigned char* hf_b = hf_a + (size_t)N_NODES * DIM;

    const int STAGE_BLOCKS = (E + 1024 * EDGES_PER_THREAD - 1) / (1024 * EDGES_PER_THREAD);
    stage_buckets<<<STAGE_BLOCKS, 1024, 0, stream>>>(src, dst, E, users, pos, neg);
    finalize_place<<<NBUCKET, 512, 0, stream>>>(emb);

    const int NQUAD = (N_NODES + 3) / 4;           // 4 nodes per wave
    const int PULL_BLOCKS = (NQUAD * 64 + 255) / 256;

    // layer 1: full pull + sampled gather (assign) + bcur reset
    pull_layer_fp8<<<PULL_BLOCKS, 256, 0, stream>>>(hf_a, hf_b, 1);

    // layer 2: full pull + sampled gather (accumulate) + chain consume
    pull_layer_fp8<<<PULL_BLOCKS, 256, 0, stream>>>(hf_b, hf_a, 2);

    // layer 3 sampled pull (4 samples/wave)
    const int SAMP_BLOCKS = ((3 * BATCH + 3) / 4 * 64 + 255) / 256;
    pull_sampled<<<SAMP_BLOCKS, 256, 0, stream>>>(hf_a, users, pos, neg);

    score_reduce<<<(BATCH * 64 + 255) / 256, 256, 0, stream>>>(emb, users, pos, neg);
    final_reduce<<<1, 256, 0, stream>>>(out);
}